// Round 3
// baseline (283.772 us; speedup 1.0000x reference)
//
#include <hip/hip_runtime.h>

// VectorQuantiser forward, MI355X fp32.
// N=65536 tokens (16x64x64, channel stride 4096), K=1024 codes, D=64.
//
// Round 3: rocprof showed k_scores VGPR_Count=52 -> zr[64] was never
// register-resident; compiler re-fetched z per code (L1-bound, VALUBusy 36%).
// Fix: k_prep transposes z into z_t[n][64] (contiguous 256B/token), k_scores
// loads it as 16 dwordx4 from one base and PINS the 64 floats with opaque
// inline asm so LLVM cannot rematerialize. launch_bounds(256,4) = 128-VGPR
// budget, 4 blocks/CU (LDS 34816B x4 = 139KB < 160KB).
// Also: en2 fused into k_prep; k_scalars+k_newemb fused into k_post;
// k_tokens codebook gather vectorized to float4.
// All rounding-sensitive fp ops bit-identical to the passing round-2 code.

#define KP 4

// ---- ws layout (bytes) ----
#define WS_ROW   0        // u64 wsrow[65536]  packed (ord(d)<<32)|~k
#define WS_COL   524288   // u64 wscol[1024]   packed (ord(d)<<32)|~n
#define WS_CNT   532480   // u32 counts[1024]
#define WS_LOSS  536576   // double loss_acc
#define WS_EN2   536592   // float en2[1024]
#define WS_CLEAR 540688   // memset only the control block
#define WS_ZT    589824   // float z_t[65536*64] = 16 MB
#define WS_BYTES (WS_ZT + 65536ull * 64 * 4)

__device__ __forceinline__ unsigned int f32_ord(float x) {
    unsigned int b = __float_as_uint(x);
    return (b & 0x80000000u) ? ~b : (b | 0x80000000u);
}

// numpy pairwise sum of squares over 64 values (8 strided chains, then
// ((r0+r1)+(r2+r3))+((r4+r5)+(r6+r7))), fp32 per-op, no contraction.
template <typename F>
__device__ __forceinline__ float np_pairwise64_sq(F get) {
    float r[8];
#pragma unroll
    for (int j = 0; j < 8; ++j) {
        float v = get(j);
        r[j] = __fmul_rn(v, v);
    }
#pragma unroll
    for (int i = 8; i < 64; i += 8) {
#pragma unroll
        for (int j = 0; j < 8; ++j) {
            float v = get(i + j);
            r[j] = __fadd_rn(r[j], __fmul_rn(v, v));
        }
    }
    return __fadd_rn(__fadd_rn(__fadd_rn(r[0], r[1]), __fadd_rn(r[2], r[3])),
                     __fadd_rn(__fadd_rn(r[4], r[5]), __fadd_rn(r[6], r[7])));
}

// ---- K_prep: transpose z -> z_t[n][64]; blocks >=1024 compute en2 ----
__global__ __launch_bounds__(256) void k_prep(const float* __restrict__ z,
                                              const float* __restrict__ emb,
                                              float* __restrict__ z_t,
                                              float* __restrict__ en2,
                                              int do_transpose) {
    if (blockIdx.x >= 1024 || !do_transpose) {
        int bx = do_transpose ? (blockIdx.x - 1024) : (int)blockIdx.x;
        int k = bx * 256 + threadIdx.x;
        if (k < 1024) {
            const float* a = emb + (size_t)k * 64;
            en2[k] = np_pairwise64_sq([&](int i) { return a[i]; });
        }
        return;
    }
    __shared__ float tile[64 * 65];
    const int t   = threadIdx.x;
    const int n0  = blockIdx.x * 64;         // 64 tokens per block
    const int b   = n0 >> 12;
    const int hw0 = n0 & 4095;
    const int l = t & 63, w = t >> 6;

    const float* zb = z + (size_t)b * 262144 + hw0 + l;
#pragma unroll
    for (int i = 0; i < 16; ++i) {
        int c = w * 16 + i;
        tile[l * 65 + c] = zb[(size_t)c * 4096];   // coalesced read
    }
    __syncthreads();
#pragma unroll
    for (int it = 0; it < 4; ++it) {
        int off = it * 1024 + t * 4;               // flat [token][chan]
        int r = off >> 6, c = off & 63;
        float4 v = make_float4(tile[r * 65 + c + 0], tile[r * 65 + c + 1],
                               tile[r * 65 + c + 2], tile[r * 65 + c + 3]);
        *reinterpret_cast<float4*>(z_t + (size_t)n0 * 64 + off) = v;  // coalesced
    }
}

// ---- K1: score matrix + row/col argmax ----
// zt_mode=1: z_any = z_t[n][64]; zt_mode=0: z_any = z (b,c,h,w strided).
__global__ __launch_bounds__(256, 4) void k_scores(
    const float* __restrict__ z_any, const float* __restrict__ emb,
    const float* __restrict__ en2,
    unsigned long long* __restrict__ wsrow,
    unsigned long long* __restrict__ wscol, int zt_mode) {
    const int t    = threadIdx.x;
    const int lane = t & 63;
    const int wave = t >> 6;
    const int n    = blockIdx.x * 256 + t;
    const int k0   = blockIdx.y * 256;

    __shared__ float tile[4][64 * 33];            // 33792 B, per-wave slabs
    __shared__ unsigned long long kbuf[4][32];    // 1 KB

    float zr[64];
    if (zt_mode) {
        // 16 dwordx4 from one base (all offsets < 4 KB immediate)
        const float4* zt4 =
            reinterpret_cast<const float4*>(z_any + (size_t)n * 64);
#pragma unroll
        for (int j = 0; j < 16; ++j) {
            float4 v = zt4[j];
            zr[4 * j + 0] = v.x; zr[4 * j + 1] = v.y;
            zr[4 * j + 2] = v.z; zr[4 * j + 3] = v.w;
        }
    } else {
        const int b = n >> 12, hw = n & 4095;
        const float* zp = z_any + (size_t)b * 262144 + hw;
#pragma unroll
        for (int c = 0; c < 64; ++c) zr[c] = zp[(size_t)c * 4096];
    }
    // Pin: opaque asm def -> LLVM cannot rematerialize the loads; the 64
    // values must stay live in VGPRs (budget 128 via launch_bounds(256,4)).
#pragma unroll
    for (int c = 0; c < 64; ++c) asm volatile("" : "+v"(zr[c]));

    const float nzn2 = -np_pairwise64_sq([&](int i) { return zr[i]; });

    float bestv = -3.4e38f;
    int   bestk = k0;

    const float4* E4 = reinterpret_cast<const float4*>(emb);
    float* mytile = tile[wave];

    for (int g = 0; g < 8; ++g) {
        const int kg = k0 + g * 32;

        for (int kk = 0; kk < 32; ++kk) {
            const int k = kg + kk;
            const float4* ek = E4 + (size_t)k * 16;   // wave-uniform -> s_load
            float c0 = 0.f, c1 = 0.f, c2 = 0.f, c3 = 0.f;
#pragma unroll
            for (int j = 0; j < 16; ++j) {
                float4 e = ek[j];
                c0 = fmaf(e.x, zr[4 * j + 0], c0);
                c1 = fmaf(e.y, zr[4 * j + 1], c1);
                c2 = fmaf(e.z, zr[4 * j + 2], c2);
                c3 = fmaf(e.w, zr[4 * j + 3], c3);
            }
            float dot = (c0 + c1) + (c2 + c3);
            // d = ((-zn2) - en2) + 2*dot, per-op fp32 like numpy
            float d = __fadd_rn(__fsub_rn(nzn2, en2[k]), 2.0f * dot);

            // row argmax: ascending k, strict > == first-index ties
            if (d > bestv) { bestv = d; bestk = k; }

            // stash for column reduction: bank (lane+kk)&31 -> 2-way, free
            mytile[lane * 33 + kk] = d;
        }
        __syncthreads();

        // column reduce: lane owns code c=lane&31, half h=lane>>5 (32 tokens)
        {
            const int c = lane & 31, h = lane >> 5;
            const float* col = mytile + (h * 32) * 33 + c;
            float bv = col[0];
            int   bt = 0;
#pragma unroll
            for (int tt = 1; tt < 32; ++tt) {
                float v = col[(size_t)tt * 33];
                if (v > bv) { bv = v; bt = tt; }   // ascending token, strict >
            }
            int nwin = blockIdx.x * 256 + wave * 64 + h * 32 + bt;
            unsigned long long key =
                ((unsigned long long)f32_ord(bv) << 32) |
                (unsigned long long)(unsigned int)(~(unsigned int)nwin);
            unsigned long long other = __shfl_xor(key, 32, 64);
            if (other > key) key = other;          // ties: larger key = smaller n
            if (h == 0) kbuf[wave][c] = key;
        }
        __syncthreads();
        if (t < 32) {
            unsigned long long m = kbuf[0][t];
#pragma unroll
            for (int w = 1; w < 4; ++w) {
                unsigned long long o = kbuf[w][t];
                m = (o > m) ? o : m;
            }
            atomicMax(&wscol[kg + t], m);
        }
        __syncthreads();
    }

    unsigned long long rowkey =
        ((unsigned long long)f32_ord(bestv) << 32) |
        (unsigned long long)(unsigned int)(~(unsigned int)bestk);
    atomicMax(&wsrow[n], rowkey);
}

// ---- K2: per-token outputs: z_q, indices, hist, loss ----
__global__ __launch_bounds__(256) void k_tokens(
    const float* __restrict__ z, const float* __restrict__ emb,
    const unsigned long long* __restrict__ wsrow,
    unsigned int* __restrict__ counts, double* __restrict__ loss_acc,
    float* __restrict__ out_zq, float* __restrict__ out_idx) {
    const int n  = blockIdx.x * 256 + threadIdx.x;
    const int b  = n >> 12;
    const int hw = n & 4095;

    unsigned long long key = wsrow[n];
    int idx = (int)(~(unsigned int)(key & 0xFFFFFFFFull));
    out_idx[n] = (float)idx;
    atomicAdd(&counts[idx], 1u);

    const float* zp = z + (size_t)b * 262144 + hw;
    float*       op = out_zq + (size_t)b * 262144 + hw;
    const float4* ep4 = reinterpret_cast<const float4*>(emb) + (size_t)idx * 16;

    double ls = 0.0;
#pragma unroll
    for (int j = 0; j < 16; ++j) {
        float4 eq = ep4[j];
        float e4[4] = {eq.x, eq.y, eq.z, eq.w};
#pragma unroll
        for (int cc = 0; cc < 4; ++cc) {
            int c = 4 * j + cc;
            float zc   = zp[(size_t)c * 4096];
            float diff = __fsub_rn(e4[cc], zc);          // fl(z_q - zc)
            float sq   = __fmul_rn(diff, diff);
            ls += (double)sq;
            op[(size_t)c * 4096] = __fadd_rn(zc, diff);  // zc + fl(z_q - zc)
        }
    }

    __shared__ double sred[256];
    sred[threadIdx.x] = ls;
    __syncthreads();
    for (int st = 128; st; st >>= 1) {
        if (threadIdx.x < st) sred[threadIdx.x] += sred[threadIdx.x + st];
        __syncthreads();
    }
    if (threadIdx.x == 0) atomicAdd(loss_acc, sred[0]);
}

// ---- K3: fused scalars (block 256) + new embedding (blocks 0..255) ----
__global__ __launch_bounds__(256) void k_post(
    const float* __restrict__ z_any,   // z_t if zt_mode else z
    const float* __restrict__ emb,
    const float* __restrict__ embed_prob,
    const unsigned long long* __restrict__ wscol,
    const unsigned int* __restrict__ counts,
    const double* __restrict__ loss_acc,
    float* __restrict__ out_loss, float* __restrict__ out_perp,
    float* __restrict__ out_newemb, float* __restrict__ out_prob,
    int zt_mode) {
    const int t = threadIdx.x;
    if (blockIdx.x == 256) {
        // scalars: 256 threads x 4 codes, fp64 tree reduce
        double s = 0.0;
        for (int j = 0; j < 4; ++j) {
            int k = t + j * 256;
            float avg  = (float)counts[k] * (1.0f / 65536.0f);
            float pnew = __fadd_rn(__fmul_rn(embed_prob[k], 0.99f),
                                   __fmul_rn(0.01f, avg));
            out_prob[k] = pnew;
            s += (double)__fmul_rn(avg, logf(__fadd_rn(avg, 1e-10f)));
        }
        __shared__ double red[256];
        red[t] = s;
        __syncthreads();
        for (int st = 128; st; st >>= 1) {
            if (t < st) red[t] += red[t + st];
            __syncthreads();
        }
        if (t == 0) {
            out_perp[0] = expf(-(float)red[0]);
            double lm = loss_acc[0] / 4194304.0;
            float  m  = (float)lm;
            out_loss[0] = __fadd_rn(__fmul_rn(0.25f, m), m);  // BETA*m + m
        }
        return;
    }
    // new embedding: 4 codes x 64 channels per block
    const int k = blockIdx.x * 4 + (t >> 6);
    const int c = t & 63;

    float avg  = (float)counts[k] * (1.0f / 65536.0f);
    float pnew = __fadd_rn(__fmul_rn(embed_prob[k], 0.99f),
                           __fmul_rn(0.01f, avg));
    float tt = __fdiv_rn(__fmul_rn(__fmul_rn(pnew, 1024.0f), 10.0f), 0.01f);
    float dk = expf(__fsub_rn(-tt, 1e-3f));
    float omd = __fsub_rn(1.0f, dk);

    unsigned long long ck = wscol[k];
    int cn = (int)(~(unsigned int)(ck & 0xFFFFFFFFull));

    float rf;
    if (zt_mode) {
        rf = z_any[(size_t)cn * 64 + c];                       // coalesced
    } else {
        int cb = cn >> 12, chw = cn & 4095;
        rf = z_any[(size_t)cb * 262144 + (size_t)c * 4096 + chw];
    }
    float e = emb[(size_t)k * 64 + c];
    out_newemb[(size_t)k * 64 + c] =
        __fadd_rn(__fmul_rn(e, omd), __fmul_rn(rf, dk));
}

extern "C" void kernel_launch(void* const* d_in, const int* in_sizes, int n_in,
                              void* d_out, int out_size, void* d_ws, size_t ws_size,
                              hipStream_t stream) {
    const float* z    = (const float*)d_in[0];   // 16*64*64*64
    const float* emb  = (const float*)d_in[1];   // 1024*64
    const float* prob = (const float*)d_in[2];   // 1024

    float* out        = (float*)d_out;
    float* out_zq     = out;                 // 4194304
    float* out_loss   = out + 4194304;       // 1
    float* out_perp   = out + 4194305;       // 1
    float* out_newemb = out + 4194306;       // 65536
    float* out_prob   = out + 4259842;       // 1024
    float* out_idx    = out + 4260866;       // 65536

    char* ws = (char*)d_ws;
    unsigned long long* wsrow = (unsigned long long*)(ws + WS_ROW);
    unsigned long long* wscol = (unsigned long long*)(ws + WS_COL);
    unsigned int*       cnts  = (unsigned int*)(ws + WS_CNT);
    double*             lacc  = (double*)(ws + WS_LOSS);
    float*              en2   = (float*)(ws + WS_EN2);
    float*              z_t   = (float*)(ws + WS_ZT);

    hipMemsetAsync(d_ws, 0, WS_CLEAR, stream);

    const int use_zt = (ws_size >= (size_t)WS_BYTES) ? 1 : 0;
    if (use_zt) {
        hipLaunchKernelGGL(k_prep, dim3(1028), dim3(256), 0, stream,
                           z, emb, z_t, en2, 1);
    } else {
        hipLaunchKernelGGL(k_prep, dim3(4), dim3(256), 0, stream,
                           z, emb, z_t, en2, 0);   // en2 only
    }
    hipLaunchKernelGGL(k_scores, dim3(256, KP), dim3(256), 0, stream,
                       use_zt ? z_t : z, emb, en2, wsrow, wscol, use_zt);
    hipLaunchKernelGGL(k_tokens, dim3(256), dim3(256), 0, stream,
                       z, emb, wsrow, cnts, lacc, out_zq, out_idx);
    hipLaunchKernelGGL(k_post, dim3(257), dim3(256), 0, stream,
                       use_zt ? z_t : z, emb, prob, wscol, cnts, lacc,
                       out_loss, out_perp, out_newemb, out_prob, use_zt);
}